// Round 8
// baseline (524.149 us; speedup 1.0000x reference)
//
#include <hip/hip_runtime.h>

typedef __attribute__((ext_vector_type(8))) short bf16x8;
typedef __attribute__((ext_vector_type(4))) float f32x4;
typedef unsigned short u16;
typedef unsigned int   u32;

#define NTOK  196
#define NH    8
#define DVDIM 128
#define CDIM  512
#define DH    1024
// 32^-0.5 * log2(e)  (log2e folded into scale; bias table pre-scaled too)
#define SCALE2 0.25505654708103197f
#define NEG_BIG -1.0e30f
#define LOG2E 1.4426950408889634f
#define VSTRIDE 200   // vT row stride (elements); keeps all b128 loads 16B-aligned
// fixed softmax shift: P = exp2(s - M). Softmax is shift-invariant; M=16 keeps
// P in [2^-40, 2^-6] for |s|<=10 (fp32/bf16 normal range; bf16 prec scale-free).
// Folded into the bias table, so the hot loop never sees it.
#define FIXED_MAX 16.0f

__device__ __forceinline__ u16 f2bf(float f) {
  u32 u = __builtin_bit_cast(u32, f);
  u32 r = u + 0x7FFFu + ((u >> 16) & 1u);   // RNE
  return (u16)(r >> 16);
}

// packed f32x2 -> bf16x2 (RNE), one VOP3 instead of 6 VALU ops (T12)
__device__ __forceinline__ u32 cvtpk(float lo, float hi) {
  u32 r;
  asm("v_cvt_pk_bf16_f32 %0, %1, %2" : "=v"(r) : "v"(lo), "v"(hi));
  return r;
}

// 16B async global->LDS.
// CONTRACT (m104/m108): global src g is PER-LANE; lds_wave_base is
// wave-uniform and HW writes lane i's data at lds_wave_base + i*16.
__device__ __forceinline__ void stage16(const void* g, char* lds_wave_base, int lane) {
#if __has_builtin(__builtin_amdgcn_global_load_lds)
  __builtin_amdgcn_global_load_lds(
      (const __attribute__((address_space(1))) unsigned int*)g,
      (__attribute__((address_space(3))) unsigned int*)lds_wave_base, 16, 0, 0);
#else
  *(uint4*)(lds_wave_base + lane * 16) = *(const uint4*)g;
#endif
}

// ---------------------------------------------------------------------------
// fp32 -> bf16 bulk convert (n8 = count/8, exact)
// ---------------------------------------------------------------------------
__global__ __launch_bounds__(256)
void cvt_k(const float* __restrict__ s, u16* __restrict__ d, int n8) {
  int i = blockIdx.x * 256 + threadIdx.x;
  if (i < n8) {
    const float4* sp = (const float4*)s + (size_t)i * 2;
    float4 a = sp[0], b = sp[1];
    uint4 o;
    o.x = (u32)f2bf(a.x) | ((u32)f2bf(a.y) << 16);
    o.y = (u32)f2bf(a.z) | ((u32)f2bf(a.w) << 16);
    o.z = (u32)f2bf(b.x) | ((u32)f2bf(b.y) << 16);
    o.w = (u32)f2bf(b.z) | ((u32)f2bf(b.w) << 16);
    ((uint4*)d)[i] = o;
  }
}

// ---------------------------------------------------------------------------
// bias table, TRANSPOSED for float4 key-contiguous reads:
// bT[h][query 224][key 256] = ab[h][bidx[query][key]] * LOG2E - FIXED_MAX,
// pads (query>=196 or key>=196) = -1e30.
// ---------------------------------------------------------------------------
__global__ __launch_bounds__(256)
void biasT_k(const float* __restrict__ ab, const int* __restrict__ bidx,
             float* __restrict__ bT) {
  const int j = threadIdx.x;     // key   0..255
  const int m = blockIdx.x;      // query 0..223
  const int h = blockIdx.y;
  float v = NEG_BIG;
  if (j < NTOK && m < NTOK)
    v = ab[h * NTOK + bidx[m * NTOK + j]] * LOG2E - FIXED_MAX;
  bT[((size_t)h * 224 + m) * 256 + j] = v;
}

// ---------------------------------------------------------------------------
// 128x128 MFMA GEMM, BK=64 (R8): half the vmcnt(0)+barrier drains of BK=32,
// 32 MFMAs amortize each drain. LDS row stride 128B requires the T2
// both-sides-or-neither swizzle with global_load_lds (rule #21, m201):
// linear LDS dest + inverse-swizzled global SOURCE (slot ^= row&7) +
// XOR-swizzled READ. D[m][n] = sum_k A[m][k] W[n][k] + bias[n].
// 1-D grid, XCD swizzle. EPI 0: scatter q/k/vT (+ zero vT pad cols).
// EPI 1: fp32 row-major + bias.
// ---------------------------------------------------------------------------
template<int K, int NB, int EPI>
__global__ __launch_bounds__(256)
void gemm_k(const u16* __restrict__ A, const u16* __restrict__ W,
            const float* __restrict__ bias,
            u16* __restrict__ q, u16* __restrict__ kk, u16* __restrict__ vT,
            float* __restrict__ out)
{
  __shared__ __align__(16) u16 As[128 * 64];   // 16 KB, logical [row][64k]
  __shared__ __align__(16) u16 Bs[128 * 64];   // swizzled: slot ^= row&7
  const int tid  = threadIdx.x;
  const int bid  = blockIdx.x;
  const int xcd  = bid & 7, t = bid >> 3;
  const int bn   = t % NB, bm = xcd * 49 + t / NB;   // 392 = 8*49
  const int lane = tid & 63, w = tid >> 6;
  const int c16  = lane & 15, quad = lane >> 4;
  const int wm   = (w >> 1) * 64, wn = (w & 1) * 64;
  f32x4 acc[4][4] = {};

  const u16* Ab = A + (size_t)bm * 128 * K;
  const u16* Wb = W + (size_t)bn * 128 * K;

  for (int k0 = 0; k0 < K; k0 += 64) {
    // stage 128x64 per matrix: 4 rounds x 256 threads x 16B. Linear LDS
    // dest byte (p*256+tid)*16; source pre-swizzled so a swizzled READ
    // sees logical [row][col].
    #pragma unroll
    for (int p = 0; p < 4; ++p) {
      const int i  = p * 256 + tid;
      const int m  = i >> 3;                       // row 0..127
      const int kp = ((i & 7) ^ (m & 7)) * 8;      // inverse-swz 16B slot
      char* dstA = (char*)As + p * 4096 + w * 1024;
      char* dstB = (char*)Bs + p * 4096 + w * 1024;
      stage16(Ab + (size_t)m * K + k0 + kp, dstA, lane);
      stage16(Wb + (size_t)m * K + k0 + kp, dstB, lane);
    }
    __syncthreads();
    #pragma unroll
    for (int kk2 = 0; kk2 < 2; ++kk2) {            // two 32-wide sub-steps
      bf16x8 af[4], bfr[4];
      #pragma unroll
      for (int mi = 0; mi < 4; ++mi) {
        const int r = wm + mi * 16 + c16;
        af[mi] = *(const bf16x8*)&As[r * 64 + (((kk2 << 2) + quad) ^ (r & 7)) * 8];
      }
      #pragma unroll
      for (int ni = 0; ni < 4; ++ni) {
        const int r = wn + ni * 16 + c16;
        bfr[ni] = *(const bf16x8*)&Bs[r * 64 + (((kk2 << 2) + quad) ^ (r & 7)) * 8];
      }
      #pragma unroll
      for (int mi = 0; mi < 4; ++mi)
        #pragma unroll
        for (int ni = 0; ni < 4; ++ni)
          acc[mi][ni] = __builtin_amdgcn_mfma_f32_16x16x32_bf16(af[mi], bfr[ni], acc[mi][ni], 0, 0, 0);
    }
    __syncthreads();
  }

  if (EPI == 0) {
    #pragma unroll
    for (int ni = 0; ni < 4; ++ni) {
      const int gn = bn * 128 + wn + ni * 16 + c16;
      const int h = gn / 192, d = gn - h * 192;
      const float bv = bias[gn];
      #pragma unroll
      for (int mi = 0; mi < 4; ++mi) {
        const int gm0 = bm * 128 + wm + mi * 16 + quad * 4;
        const int bb = gm0 / 196, tok0 = gm0 - bb * 196;  // tok0..tok0+3 same batch
        const size_t bhh = (size_t)bb * 8 + h;
        const float v0 = acc[mi][ni][0] + bv, v1 = acc[mi][ni][1] + bv;
        const float v2 = acc[mi][ni][2] + bv, v3 = acc[mi][ni][3] + bv;
        if (d < 64) {
          u16* dst = (d < 32) ? (q  + (bhh * 196 + tok0) * 32 + d)
                              : (kk + (bhh * 196 + tok0) * 32 + (d - 32));
          dst[0] = f2bf(v0); dst[32] = f2bf(v1); dst[64] = f2bf(v2); dst[96] = f2bf(v3);
        } else {
          ushort4 pk = { f2bf(v0), f2bf(v1), f2bf(v2), f2bf(v3) };
          u16* vrow = vT + (bhh * 128 + (d - 64)) * VSTRIDE;
          *(ushort4*)&vrow[tok0] = pk;
          if (tok0 == 192) {               // zero pad cols 196..199 once/row
            ushort4 z = {0, 0, 0, 0};
            *(ushort4*)&vrow[196] = z;
          }
        }
      }
    }
  } else {
    #pragma unroll
    for (int ni = 0; ni < 4; ++ni) {
      const int gn = bn * 128 + wn + ni * 16 + c16;
      const float bv = bias[gn];
      #pragma unroll
      for (int mi = 0; mi < 4; ++mi) {
        const int gm0 = bm * 128 + wm + mi * 16 + quad * 4;
        #pragma unroll
        for (int r = 0; r < 4; ++r)
          out[(size_t)(gm0 + r) * CDIM + gn] = acc[mi][ni][r] + bv;
      }
    }
  }
}

// ---------------------------------------------------------------------------
// Attention, S^T formulation. grid 2048 (one block per bh) x 256 threads.
// FROZEN from R7 (proven 504 us total): K + full V^T in LDS once per block,
// barrier-free tile loop, FIXED-MAX softmax (no online max/rescale; M folded
// into bias table), float4 bias reads, lsum reduced once per tile.
// ---------------------------------------------------------------------------
__global__ __launch_bounds__(256)
void attn_k(const u16* __restrict__ q, const u16* __restrict__ kk,
            const u16* __restrict__ vT, const float* __restrict__ bT,
            u16* __restrict__ Ob)
{
  // manual LDS layout (single allocation, exact 80,896 B => 2 blocks/CU):
  //   k_lds  @      0: 256 rows x 40 elem x 2B = 20,480  [key][kd], stride 40
  //   vt_lds @ 20,480: 128 rows x 200 elem x 2B = 51,200 [dv][key], packed
  //   p_lds  @ 71,680: 4 waves x 16 x 72 x 2B   =  9,216 [query][key]
  __shared__ __align__(16) char smem[80896];
  u16* k_lds  = (u16*)smem;
  u16* vt_lds = (u16*)(smem + 20480);
  u16* p_lds  = (u16*)(smem + 71680);

  const int bh = blockIdx.x;
  const int b = bh >> 3, h = bh & 7;
  const int tid = threadIdx.x;
  const int lane = tid & 63, w = tid >> 6;
  const int c16 = lane & 15, quad = lane >> 4;
  const u16* qb = q  + (size_t)bh * (NTOK * 32);
  const u16* kb = kk + (size_t)bh * (NTOK * 32);
  const u16* vb = vT + (size_t)bh * (DVDIM * VSTRIDE);
  const float* bTh = bT + (size_t)h * 224 * 256;
  const f32x4 zf = {0.f, 0.f, 0.f, 0.f};
  u16* pw = p_lds + w * 16 * 72;

  // ---- stage V^T once: 51,200 B packed => 50 x 1024 B wave-chunks (async).
  // Global src per-lane (+ lane*16); LDS dest wave-uniform chunk base.
  {
    const char* vbb = (const char*)vb;
    for (int c = w; c < 50; c += 4)
      stage16(vbb + c * 1024 + lane * 16, (char*)vt_lds + c * 1024, lane);
  }
  // ---- stage K once: 256 rows (rows >=196 dup row 195; killed by -1e30 bias)
  #pragma unroll
  for (int p = 0; p < 4; ++p) {
    const int i = p * 256 + tid;
    const int row = i >> 2, part = (i & 3) * 8;
    const uint4 val = *(const uint4*)(kb + (size_t)min(row, NTOK - 1) * 32 + part);
    *(uint4*)&k_lds[row * 40 + part] = val;
  }
  __syncthreads();                                  // drains vmcnt (async V) + lgkm
  {                                                 // zero V pad cols 196..199
    const int row = tid >> 1, half = tid & 1;
    *(u32*)&vt_lds[row * VSTRIDE + 196 + half * 2] = 0u;
  }
  __syncthreads();

  // ---- tile loop: waves own tiles {w, w+4, w+8}; tile 12 -> wave (bh&3)
  const int nt_iter = 3 + ((w == (bh & 3)) ? 1 : 0);
  for (int t = 0; t < nt_iter; ++t) {
    const int ti = (t < 3) ? (w + 4 * t) : 12;
    const int tok = min(ti * 16 + c16, NTOK - 1);
    const bf16x8 qf = *(const bf16x8*)(qb + (size_t)tok * 32 + quad * 8);
    const int qg = min(ti * 16 + c16, 223);
    float lsum = 0.f;                               // per-lane partial (own keys)
    f32x4 oacc[8] = {};
    const float* brow = bTh + (size_t)qg * 256;     // bias row for this query

    for (int kc = 0; kc < 4; ++kc) {
      // bias for this chunk: 4 float4 (keys contiguous), independent of MFMA
      float4 bv4[4];
      #pragma unroll
      for (int nt = 0; nt < 4; ++nt)
        bv4[nt] = *(const float4*)(brow + kc * 64 + nt * 16 + quad * 4);

      // ---- QK^T: S^T[key][query] = K*Q^T
      f32x4 sc[4];
      __builtin_amdgcn_s_setprio(1);
      #pragma unroll
      for (int nt = 0; nt < 4; ++nt) {
        bf16x8 kf = *(const bf16x8*)&k_lds[(kc * 64 + nt * 16 + c16) * 40 + quad * 8];
        sc[nt] = __builtin_amdgcn_mfma_f32_16x16x32_bf16(kf, qf, zf, 0, 0, 0);
      }
      __builtin_amdgcn_s_setprio(0);

      // ---- fixed-max softmax: P = exp2(s*SCALE2 + (bias - M)); no max
      // tracking, no rescale. Pads: bias=-1e30 -> exp2 -> 0 exactly.
      #pragma unroll
      for (int nt = 0; nt < 4; ++nt) {
        const float p0 = exp2f(sc[nt][0] * SCALE2 + bv4[nt].x);
        const float p1 = exp2f(sc[nt][1] * SCALE2 + bv4[nt].y);
        const float p2 = exp2f(sc[nt][2] * SCALE2 + bv4[nt].z);
        const float p3 = exp2f(sc[nt][3] * SCALE2 + bv4[nt].w);
        lsum += (p0 + p1) + (p2 + p3);
        uint2 pk;
        pk.x = cvtpk(p0, p1);                       // T12
        pk.y = cvtpk(p2, p3);
        *(uint2*)&pw[c16 * 72 + nt * 16 + quad * 4] = pk;
      }

      // ---- PV: O += P * V (same-wave LDS round-trip: in order)
      __builtin_amdgcn_s_setprio(1);
      #pragma unroll
      for (int ks = 0; ks < 2; ++ks) {
        bf16x8 ap = *(const bf16x8*)&pw[c16 * 72 + ks * 32 + quad * 8];
        #pragma unroll
        for (int nt = 0; nt < 8; ++nt) {
          bf16x8 bv = *(const bf16x8*)&vt_lds[(nt * 16 + c16) * VSTRIDE + kc * 64 + ks * 32 + quad * 8];
          oacc[nt] = __builtin_amdgcn_mfma_f32_16x16x32_bf16(ap, bv, oacc[nt], 0, 0, 0);
        }
      }
      __builtin_amdgcn_s_setprio(0);
    }

    // ---- reduce lsum across quads ONCE per tile (was per-chunk)
    lsum += __shfl_xor(lsum, 16);
    lsum += __shfl_xor(lsum, 32);

    // ---- epilogue for this tile
    float lr[4];
    #pragma unroll
    for (int r = 0; r < 4; ++r) lr[r] = __shfl(lsum, quad * 4 + r);
    #pragma unroll
    for (int r = 0; r < 4; ++r) {
      const int m = ti * 16 + quad * 4 + r;
      if (m < NTOK) {
        const float inv = 1.0f / lr[r];
        #pragma unroll
        for (int nt = 0; nt < 8; ++nt)
          Ob[((size_t)b * NTOK + m) * DH + h * DVDIM + nt * 16 + c16] =
              f2bf(oacc[nt][r] * inv);
      }
    }
  }
}

// ---------------------------------------------------------------------------
extern "C" void kernel_launch(void* const* d_in, const int* in_sizes, int n_in,
                              void* d_out, int out_size, void* d_ws, size_t ws_size,
                              hipStream_t stream) {
  const float* x      = (const float*)d_in[0];   // (256,196,512)
  const float* qkv_w  = (const float*)d_in[1];   // (1536,512)
  const float* qkv_b  = (const float*)d_in[2];   // (1536,)
  const float* proj_w = (const float*)d_in[3];   // (512,1024)
  const float* proj_b = (const float*)d_in[4];   // (512,)
  const float* ab     = (const float*)d_in[5];   // (8,49)
  const int*   bidx   = (const int*)d_in[6];     // (196,196) int32
  float* out = (float*)d_out;                    // (256,196,512) fp32

  char* p = (char*)d_ws;
  u16*   qw  = (u16*)(p);                        // 25,690,112 B
  u16*   kw  = (u16*)(p + 25690112);             // 25,690,112 B
  u16*   vTw = (u16*)(p + 51380224);             // 104,857,600 B [bh][128][200]
  u16*   w1b = (u16*)(p + 156237824);            // 1,572,864 B
  u16*   w3b = (u16*)(p + 157810688);            // 1,048,576 B
  float* bT  = (float*)(p + 158859264);          // 1,835,008 B [8][224][256]
  u16*   xb  = (u16*)(p + 160694272);            // 51,380,224 B (dead after gemm1)
  u16*   Ob  = (u16*)(p + 160694272);            // 102,760,448 B (aliases xb; safe)

  // precompute: bf16 casts + bias table (transposed, -FIXED_MAX folded)
  cvt_k<<<12544, 256, 0, stream>>>(x,      xb,  3211264);
  cvt_k<<<  384, 256, 0, stream>>>(qkv_w,  w1b,   98304);
  cvt_k<<<  256, 256, 0, stream>>>(proj_w, w3b,   65536);
  biasT_k<<<dim3(224, 8), 256, 0, stream>>>(ab, bidx, bT);

  // QKV GEMM: M=50176(392), N=1536(12), K=512 ; scatter q/k/vT (+V pad zero)
  gemm_k<512, 12, 0><<<4704, 256, 0, stream>>>(xb, w1b, qkv_b, qw, kw, vTw, nullptr);

  // attention: one block per bh, KV resident in LDS
  attn_k<<<2048, 256, 0, stream>>>(qw, kw, vTw, bT, Ob);

  // proj GEMM: M=50176, N=512(4), K=1024 ; fp32 out + bias
  gemm_k<1024, 4, 1><<<1568, 256, 0, stream>>>(Ob, w3b, proj_b, nullptr, nullptr, nullptr, out);
}

// Round 9
// 496.264 us; speedup vs baseline: 1.0562x; 1.0562x over previous
//
#include <hip/hip_runtime.h>

typedef __attribute__((ext_vector_type(8))) short bf16x8;
typedef __attribute__((ext_vector_type(4))) float f32x4;
typedef unsigned short u16;
typedef unsigned int   u32;

#define NTOK  196
#define NH    8
#define DVDIM 128
#define CDIM  512
#define DH    1024
// 32^-0.5 * log2(e)  (log2e folded into scale; bias table pre-scaled too)
#define SCALE2 0.25505654708103197f
#define NEG_BIG -1.0e30f
#define LOG2E 1.4426950408889634f
#define VSTRIDE 200   // vT row stride (elements); keeps all b128 loads 16B-aligned
// fixed softmax shift: P = exp2(s - M). Softmax is shift-invariant; M=16 keeps
// P in [2^-40, 2^-6] for |s|<=10 (fp32/bf16 normal range; bf16 prec scale-free).
// Folded into the bias table, so the hot loop never sees it.
#define FIXED_MAX 16.0f

__device__ __forceinline__ u16 f2bf(float f) {
  u32 u = __builtin_bit_cast(u32, f);
  u32 r = u + 0x7FFFu + ((u >> 16) & 1u);   // RNE
  return (u16)(r >> 16);
}

// packed f32x2 -> bf16x2 (RNE), one VOP3 instead of 6 VALU ops (T12)
__device__ __forceinline__ u32 cvtpk(float lo, float hi) {
  u32 r;
  asm("v_cvt_pk_bf16_f32 %0, %1, %2" : "=v"(r) : "v"(lo), "v"(hi));
  return r;
}

// 16B async global->LDS.
// CONTRACT (m104/m108): global src g is PER-LANE; lds_wave_base is
// wave-uniform and HW writes lane i's data at lds_wave_base + i*16.
__device__ __forceinline__ void stage16(const void* g, char* lds_wave_base, int lane) {
#if __has_builtin(__builtin_amdgcn_global_load_lds)
  __builtin_amdgcn_global_load_lds(
      (const __attribute__((address_space(1))) unsigned int*)g,
      (__attribute__((address_space(3))) unsigned int*)lds_wave_base, 16, 0, 0);
#else
  *(uint4*)(lds_wave_base + lane * 16) = *(const uint4*)g;
#endif
}

// ---------------------------------------------------------------------------
// fp32 -> bf16 bulk convert (n8 = count/8, exact)
// ---------------------------------------------------------------------------
__global__ __launch_bounds__(256)
void cvt_k(const float* __restrict__ s, u16* __restrict__ d, int n8) {
  int i = blockIdx.x * 256 + threadIdx.x;
  if (i < n8) {
    const float4* sp = (const float4*)s + (size_t)i * 2;
    float4 a = sp[0], b = sp[1];
    uint4 o;
    o.x = (u32)f2bf(a.x) | ((u32)f2bf(a.y) << 16);
    o.y = (u32)f2bf(a.z) | ((u32)f2bf(a.w) << 16);
    o.z = (u32)f2bf(b.x) | ((u32)f2bf(b.y) << 16);
    o.w = (u32)f2bf(b.z) | ((u32)f2bf(b.w) << 16);
    ((uint4*)d)[i] = o;
  }
}

// ---------------------------------------------------------------------------
// bias table, TRANSPOSED for float4 key-contiguous reads:
// bT[h][query 224][key 256] = ab[h][bidx[query][key]] * LOG2E - FIXED_MAX,
// pads (query>=196 or key>=196) = -1e30.
// ---------------------------------------------------------------------------
__global__ __launch_bounds__(256)
void biasT_k(const float* __restrict__ ab, const int* __restrict__ bidx,
             float* __restrict__ bT) {
  const int j = threadIdx.x;     // key   0..255
  const int m = blockIdx.x;      // query 0..223
  const int h = blockIdx.y;
  float v = NEG_BIG;
  if (j < NTOK && m < NTOK)
    v = ab[h * NTOK + bidx[m * NTOK + j]] * LOG2E - FIXED_MAX;
  bT[((size_t)h * 224 + m) * 256 + j] = v;
}

// ---------------------------------------------------------------------------
// 128x128 MFMA GEMM, BK=32 (R7 shell: 16 KB LDS, same occupancy) + R9
// conflict-free XOR swizzle. Row = 4x16B slots; physical slot =
// logical ^ ((row>>1)&3) cycles all 8 bank-groups over 8 rows -> 2-way
// aliasing (free, m136) instead of 8-way. Both-sides-or-neither (rule #21):
// inverse-swizzled global SOURCE + linear LDS dest + swizzled READ.
// D[m][n] = sum_k A[m][k] W[n][k] + bias[n]. 1-D grid, XCD swizzle.
// EPI 0: scatter q/k/vT (+ zero vT pad cols). EPI 1: fp32 + bias.
// ---------------------------------------------------------------------------
template<int K, int NB, int EPI>
__global__ __launch_bounds__(256)
void gemm_k(const u16* __restrict__ A, const u16* __restrict__ W,
            const float* __restrict__ bias,
            u16* __restrict__ q, u16* __restrict__ kk, u16* __restrict__ vT,
            float* __restrict__ out)
{
  __shared__ __align__(16) u16 As[128 * 32];
  __shared__ __align__(16) u16 Bs[128 * 32];
  const int tid  = threadIdx.x;
  const int bid  = blockIdx.x;
  const int xcd  = bid & 7, t = bid >> 3;
  const int bn   = t % NB, bm = xcd * 49 + t / NB;   // 392 = 8*49
  const int lane = tid & 63, w = tid >> 6;
  const int c16  = lane & 15, quad = lane >> 4;
  const int wm   = (w >> 1) * 64, wn = (w & 1) * 64;
  f32x4 acc[4][4] = {};

  const u16* Ab = A + (size_t)bm * 128 * K;
  const u16* Wb = W + (size_t)bn * 128 * K;
  char* ldsA = (char*)As + w * 1024;
  char* ldsB = (char*)Bs + w * 1024;

  for (int k0 = 0; k0 < K; k0 += 32) {
    #pragma unroll
    for (int p = 0; p < 2; ++p) {
      const int i = p * 256 + tid;
      const int m = i >> 2;
      const int kp = ((i & 3) ^ ((m >> 1) & 3)) * 8;   // inverse-swz slot
      stage16(Ab + (size_t)m * K + k0 + kp, ldsA + p * 4096, lane);
      stage16(Wb + (size_t)m * K + k0 + kp, ldsB + p * 4096, lane);
    }
    __syncthreads();
    bf16x8 af[4], bfr[4];
    #pragma unroll
    for (int mi = 0; mi < 4; ++mi) {
      const int r = wm + mi * 16 + c16;
      af[mi] = *(const bf16x8*)&As[r * 32 + ((quad ^ ((r >> 1) & 3)) * 8)];
    }
    #pragma unroll
    for (int ni = 0; ni < 4; ++ni) {
      const int r = wn + ni * 16 + c16;
      bfr[ni] = *(const bf16x8*)&Bs[r * 32 + ((quad ^ ((r >> 1) & 3)) * 8)];
    }
    #pragma unroll
    for (int mi = 0; mi < 4; ++mi)
      #pragma unroll
      for (int ni = 0; ni < 4; ++ni)
        acc[mi][ni] = __builtin_amdgcn_mfma_f32_16x16x32_bf16(af[mi], bfr[ni], acc[mi][ni], 0, 0, 0);
    __syncthreads();
  }

  if (EPI == 0) {
    #pragma unroll
    for (int ni = 0; ni < 4; ++ni) {
      const int gn = bn * 128 + wn + ni * 16 + c16;
      const int h = gn / 192, d = gn - h * 192;
      const float bv = bias[gn];
      #pragma unroll
      for (int mi = 0; mi < 4; ++mi) {
        const int gm0 = bm * 128 + wm + mi * 16 + quad * 4;
        const int bb = gm0 / 196, tok0 = gm0 - bb * 196;  // tok0..tok0+3 same batch
        const size_t bhh = (size_t)bb * 8 + h;
        const float v0 = acc[mi][ni][0] + bv, v1 = acc[mi][ni][1] + bv;
        const float v2 = acc[mi][ni][2] + bv, v3 = acc[mi][ni][3] + bv;
        if (d < 64) {
          u16* dst = (d < 32) ? (q  + (bhh * 196 + tok0) * 32 + d)
                              : (kk + (bhh * 196 + tok0) * 32 + (d - 32));
          dst[0] = f2bf(v0); dst[32] = f2bf(v1); dst[64] = f2bf(v2); dst[96] = f2bf(v3);
        } else {
          ushort4 pk = { f2bf(v0), f2bf(v1), f2bf(v2), f2bf(v3) };
          u16* vrow = vT + (bhh * 128 + (d - 64)) * VSTRIDE;
          *(ushort4*)&vrow[tok0] = pk;
          if (tok0 == 192) {               // zero pad cols 196..199 once/row
            ushort4 z = {0, 0, 0, 0};
            *(ushort4*)&vrow[196] = z;
          }
        }
      }
    }
  } else {
    #pragma unroll
    for (int ni = 0; ni < 4; ++ni) {
      const int gn = bn * 128 + wn + ni * 16 + c16;
      const float bv = bias[gn];
      #pragma unroll
      for (int mi = 0; mi < 4; ++mi) {
        const int gm0 = bm * 128 + wm + mi * 16 + quad * 4;
        #pragma unroll
        for (int r = 0; r < 4; ++r)
          out[(size_t)(gm0 + r) * CDIM + gn] = acc[mi][ni][r] + bv;
      }
    }
  }
}

// ---------------------------------------------------------------------------
// Attention, S^T formulation. grid 2048 (one block per bh) x 256 threads.
// FROZEN from R7 (proven 504 us total): K + full V^T in LDS once per block,
// barrier-free tile loop, FIXED-MAX softmax (no online max/rescale; M folded
// into bias table), float4 bias reads, lsum reduced once per tile.
// ---------------------------------------------------------------------------
__global__ __launch_bounds__(256)
void attn_k(const u16* __restrict__ q, const u16* __restrict__ kk,
            const u16* __restrict__ vT, const float* __restrict__ bT,
            u16* __restrict__ Ob)
{
  // manual LDS layout (single allocation, exact 80,896 B => 2 blocks/CU):
  //   k_lds  @      0: 256 rows x 40 elem x 2B = 20,480  [key][kd], stride 40
  //   vt_lds @ 20,480: 128 rows x 200 elem x 2B = 51,200 [dv][key], packed
  //   p_lds  @ 71,680: 4 waves x 16 x 72 x 2B   =  9,216 [query][key]
  __shared__ __align__(16) char smem[80896];
  u16* k_lds  = (u16*)smem;
  u16* vt_lds = (u16*)(smem + 20480);
  u16* p_lds  = (u16*)(smem + 71680);

  const int bh = blockIdx.x;
  const int b = bh >> 3, h = bh & 7;
  const int tid = threadIdx.x;
  const int lane = tid & 63, w = tid >> 6;
  const int c16 = lane & 15, quad = lane >> 4;
  const u16* qb = q  + (size_t)bh * (NTOK * 32);
  const u16* kb = kk + (size_t)bh * (NTOK * 32);
  const u16* vb = vT + (size_t)bh * (DVDIM * VSTRIDE);
  const float* bTh = bT + (size_t)h * 224 * 256;
  const f32x4 zf = {0.f, 0.f, 0.f, 0.f};
  u16* pw = p_lds + w * 16 * 72;

  // ---- stage V^T once: 51,200 B packed => 50 x 1024 B wave-chunks (async).
  // Global src per-lane (+ lane*16); LDS dest wave-uniform chunk base.
  {
    const char* vbb = (const char*)vb;
    for (int c = w; c < 50; c += 4)
      stage16(vbb + c * 1024 + lane * 16, (char*)vt_lds + c * 1024, lane);
  }
  // ---- stage K once: 256 rows (rows >=196 dup row 195; killed by -1e30 bias)
  #pragma unroll
  for (int p = 0; p < 4; ++p) {
    const int i = p * 256 + tid;
    const int row = i >> 2, part = (i & 3) * 8;
    const uint4 val = *(const uint4*)(kb + (size_t)min(row, NTOK - 1) * 32 + part);
    *(uint4*)&k_lds[row * 40 + part] = val;
  }
  __syncthreads();                                  // drains vmcnt (async V) + lgkm
  {                                                 // zero V pad cols 196..199
    const int row = tid >> 1, half = tid & 1;
    *(u32*)&vt_lds[row * VSTRIDE + 196 + half * 2] = 0u;
  }
  __syncthreads();

  // ---- tile loop: waves own tiles {w, w+4, w+8}; tile 12 -> wave (bh&3)
  const int nt_iter = 3 + ((w == (bh & 3)) ? 1 : 0);
  for (int t = 0; t < nt_iter; ++t) {
    const int ti = (t < 3) ? (w + 4 * t) : 12;
    const int tok = min(ti * 16 + c16, NTOK - 1);
    const bf16x8 qf = *(const bf16x8*)(qb + (size_t)tok * 32 + quad * 8);
    const int qg = min(ti * 16 + c16, 223);
    float lsum = 0.f;                               // per-lane partial (own keys)
    f32x4 oacc[8] = {};
    const float* brow = bTh + (size_t)qg * 256;     // bias row for this query

    for (int kc = 0; kc < 4; ++kc) {
      // bias for this chunk: 4 float4 (keys contiguous), independent of MFMA
      float4 bv4[4];
      #pragma unroll
      for (int nt = 0; nt < 4; ++nt)
        bv4[nt] = *(const float4*)(brow + kc * 64 + nt * 16 + quad * 4);

      // ---- QK^T: S^T[key][query] = K*Q^T
      f32x4 sc[4];
      __builtin_amdgcn_s_setprio(1);
      #pragma unroll
      for (int nt = 0; nt < 4; ++nt) {
        bf16x8 kf = *(const bf16x8*)&k_lds[(kc * 64 + nt * 16 + c16) * 40 + quad * 8];
        sc[nt] = __builtin_amdgcn_mfma_f32_16x16x32_bf16(kf, qf, zf, 0, 0, 0);
      }
      __builtin_amdgcn_s_setprio(0);

      // ---- fixed-max softmax: P = exp2(s*SCALE2 + (bias - M)); no max
      // tracking, no rescale. Pads: bias=-1e30 -> exp2 -> 0 exactly.
      #pragma unroll
      for (int nt = 0; nt < 4; ++nt) {
        const float p0 = exp2f(sc[nt][0] * SCALE2 + bv4[nt].x);
        const float p1 = exp2f(sc[nt][1] * SCALE2 + bv4[nt].y);
        const float p2 = exp2f(sc[nt][2] * SCALE2 + bv4[nt].z);
        const float p3 = exp2f(sc[nt][3] * SCALE2 + bv4[nt].w);
        lsum += (p0 + p1) + (p2 + p3);
        uint2 pk;
        pk.x = cvtpk(p0, p1);                       // T12
        pk.y = cvtpk(p2, p3);
        *(uint2*)&pw[c16 * 72 + nt * 16 + quad * 4] = pk;
      }

      // ---- PV: O += P * V (same-wave LDS round-trip: in order)
      __builtin_amdgcn_s_setprio(1);
      #pragma unroll
      for (int ks = 0; ks < 2; ++ks) {
        bf16x8 ap = *(const bf16x8*)&pw[c16 * 72 + ks * 32 + quad * 8];
        #pragma unroll
        for (int nt = 0; nt < 8; ++nt) {
          bf16x8 bv = *(const bf16x8*)&vt_lds[(nt * 16 + c16) * VSTRIDE + kc * 64 + ks * 32 + quad * 8];
          oacc[nt] = __builtin_amdgcn_mfma_f32_16x16x32_bf16(ap, bv, oacc[nt], 0, 0, 0);
        }
      }
      __builtin_amdgcn_s_setprio(0);
    }

    // ---- reduce lsum across quads ONCE per tile (was per-chunk)
    lsum += __shfl_xor(lsum, 16);
    lsum += __shfl_xor(lsum, 32);

    // ---- epilogue for this tile
    float lr[4];
    #pragma unroll
    for (int r = 0; r < 4; ++r) lr[r] = __shfl(lsum, quad * 4 + r);
    #pragma unroll
    for (int r = 0; r < 4; ++r) {
      const int m = ti * 16 + quad * 4 + r;
      if (m < NTOK) {
        const float inv = 1.0f / lr[r];
        #pragma unroll
        for (int nt = 0; nt < 8; ++nt)
          Ob[((size_t)b * NTOK + m) * DH + h * DVDIM + nt * 16 + c16] =
              f2bf(oacc[nt][r] * inv);
      }
    }
  }
}

// ---------------------------------------------------------------------------
extern "C" void kernel_launch(void* const* d_in, const int* in_sizes, int n_in,
                              void* d_out, int out_size, void* d_ws, size_t ws_size,
                              hipStream_t stream) {
  const float* x      = (const float*)d_in[0];   // (256,196,512)
  const float* qkv_w  = (const float*)d_in[1];   // (1536,512)
  const float* qkv_b  = (const float*)d_in[2];   // (1536,)
  const float* proj_w = (const float*)d_in[3];   // (512,1024)
  const float* proj_b = (const float*)d_in[4];   // (512,)
  const float* ab     = (const float*)d_in[5];   // (8,49)
  const int*   bidx   = (const int*)d_in[6];     // (196,196) int32
  float* out = (float*)d_out;                    // (256,196,512) fp32

  char* p = (char*)d_ws;
  u16*   qw  = (u16*)(p);                        // 25,690,112 B
  u16*   kw  = (u16*)(p + 25690112);             // 25,690,112 B
  u16*   vTw = (u16*)(p + 51380224);             // 104,857,600 B [bh][128][200]
  u16*   w1b = (u16*)(p + 156237824);            // 1,572,864 B
  u16*   w3b = (u16*)(p + 157810688);            // 1,048,576 B
  float* bT  = (float*)(p + 158859264);          // 1,835,008 B [8][224][256]
  u16*   xb  = (u16*)(p + 160694272);            // 51,380,224 B (dead after gemm1)
  u16*   Ob  = (u16*)(p + 160694272);            // 102,760,448 B (aliases xb; safe)

  // precompute: bf16 casts + bias table (transposed, -FIXED_MAX folded)
  cvt_k<<<12544, 256, 0, stream>>>(x,      xb,  3211264);
  cvt_k<<<  384, 256, 0, stream>>>(qkv_w,  w1b,   98304);
  cvt_k<<<  256, 256, 0, stream>>>(proj_w, w3b,   65536);
  biasT_k<<<dim3(224, 8), 256, 0, stream>>>(ab, bidx, bT);

  // QKV GEMM: M=50176(392), N=1536(12), K=512 ; scatter q/k/vT (+V pad zero)
  gemm_k<512, 12, 0><<<4704, 256, 0, stream>>>(xb, w1b, qkv_b, qw, kw, vTw, nullptr);

  // attention: one block per bh, KV resident in LDS
  attn_k<<<2048, 256, 0, stream>>>(qw, kw, vTw, bT, Ob);

  // proj GEMM: M=50176, N=512(4), K=1024 ; fp32 out + bias
  gemm_k<1024, 4, 1><<<1568, 256, 0, stream>>>(Ob, w3b, proj_b, nullptr, nullptr, nullptr, out);
}